// Round 4
// baseline (191.290 us; speedup 1.0000x reference)
//
#include <hip/hip_runtime.h>
#include <math.h>

// B=4, H=16, N=4096, D=128 -> 64 independent scan rows of length 4096.
static constexpr int ROWS = 64;
static constexpr int NSEQ = 4096;
static constexpr int DIM  = 128;
static constexpr int SC   = 32;              // scalar sub-chunk length
static constexpr int SPR  = NSEQ / SC;       // 128 sub-chunks per row
static constexpr int NSC  = ROWS * SPR;      // 8192 sub-chunks
static constexpr int VC   = 64;              // vector chunk length
static constexpr int VPR  = NSEQ / VC;       // 64 chunks per row
static constexpr int NVC  = ROWS * VPR;      // 4096 vector chunks

// ---------------------------------------------------------------------------
// k_alpha v2: wave64 per 64-timestep tile; LANE OWNS A TIMESTEP.
// Lane l reads its own q/k row (32 dwordx4 each, lane-sequential; 64B lines
// fully consumed within 4 instrs -> L1 absorbs the transient overfetch) and
// accumulates the dot in-lane: no per-timestep shfl chains at all. Loads are
// batched 16-deep into arrays (separate loop from the FMAs) for real MLP.
// Per-32-half stats (M, D) via one butterfly at tile end.
// ---------------------------------------------------------------------------
__global__ __launch_bounds__(256) void k_alpha(
    const float* __restrict__ q, const float* __restrict__ k,
    float* __restrict__ alpha, float* __restrict__ cM, float* __restrict__ cD)
{
    const int lane = threadIdx.x & 63;
    const int tile = blockIdx.x * 4 + (threadIdx.x >> 6);   // 64-t tile id
    const float4* qrow = (const float4*)(q + (size_t)tile * (64 * DIM) + lane * DIM);
    const float4* krow = (const float4*)(k + (size_t)tile * (64 * DIM) + lane * DIM);

    float ax = 0.f, ay = 0.f, az = 0.f, aw = 0.f;
    for (int u0 = 0; u0 < DIM / 4; u0 += 8) {
        float4 qa[8], ka[8];
        #pragma unroll
        for (int u = 0; u < 8; ++u) qa[u] = qrow[u0 + u];
        #pragma unroll
        for (int u = 0; u < 8; ++u) ka[u] = krow[u0 + u];
        #pragma unroll
        for (int u = 0; u < 8; ++u) {
            ax += qa[u].x * ka[u].x;  ay += qa[u].y * ka[u].y;
            az += qa[u].z * ka[u].z;  aw += qa[u].w * ka[u].w;
        }
    }
    const float a = (ax + ay) + (az + aw);   // alpha for timestep = lane

    // per-32-lane-half running max (masks <=16 stay within each half)
    float mRun = a;
    #pragma unroll
    for (int m = 16; m >= 1; m >>= 1) mRun = fmaxf(mRun, __shfl_xor(mRun, m));
    float e = __expf(a - mRun);
    #pragma unroll
    for (int m = 16; m >= 1; m >>= 1) e += __shfl_xor(e, m);

    alpha[tile * 64 + lane] = a;             // coalesced; matches alpha[s*SC+l]
    if ((lane & 31) == 0) {
        const int s = tile * 2 + (lane >> 5);   // sub-chunk id (SC=32)
        cM[s] = mRun; cD[s] = e;
    }
}

// ---------------------------------------------------------------------------
// k_scan: per row (64 blocks):
//  A) stage cM/cD into LDS
//  1) thread-0 serial exclusive scan over 128 sub-chunks -> pM,pD
//  2) per-sub-chunk coefficient chains -> coefCW[t] = (c_t, w_t) global coeffs
// ---------------------------------------------------------------------------
__global__ __launch_bounds__(256) void k_scan(
    const float* __restrict__ alpha, const float* __restrict__ cM,
    const float* __restrict__ cD,
    float* __restrict__ pM, float* __restrict__ pD, float2* __restrict__ coefCW)
{
    __shared__ float lM[SPR], lD[SPR], lpM[SPR], lpD[SPR];
    const int row  = blockIdx.x;
    const int lane = threadIdx.x & 31;
    const int g    = threadIdx.x >> 5;     // 0..7

    if (threadIdx.x < SPR) {
        lM[threadIdx.x] = cM[row * SPR + threadIdx.x];
        lD[threadIdx.x] = cD[row * SPR + threadIdx.x];
    }
    __syncthreads();

    if (threadIdx.x == 0) {
        float m = -INFINITY, d = 0.f;
        for (int sl = 0; sl < SPR; ++sl) {
            lpM[sl] = m; lpD[sl] = d;
            pM[row * SPR + sl] = m; pD[row * SPR + sl] = d;
            const float M = lM[sl], D = lD[sl];
            const float mn = fmaxf(m, M);
            d = d * __expf(m - mn) + D * __expf(M - mn);
            m = mn;
        }
    }
    __syncthreads();

    for (int sl = g; sl < SPR; sl += 8) {
        const int s = row * SPR + sl;
        const float a = alpha[s * SC + lane];
        float m = lpM[sl];
        float cK = 0.f, wK = 0.f;
        for (int t = 0; t < SC; ++t) {
            const float at = __shfl(a, t, 32);
            const float mn = fmaxf(m, at);
            const float c  = __expf(m - mn);     // exp(-inf)=0 on first step
            const float w  = __expf(at - mn);
            cK = (t == lane) ? c : cK;
            wK = (t == lane) ? w : wK;
            m = mn;
        }
        coefCW[s * SC + lane] = make_float2(cK, wK);
    }
}

// ---------------------------------------------------------------------------
// k_agg: per vector chunk (one wave, lane owns 2 dims): n'_C via the global
// coefficient recurrence seeded 0. Result is normalized at the chunk-end
// global max (pM[2C+2]) so the prefix combine factor is exp(pM[2C]-pM[2C+2]).
// ---------------------------------------------------------------------------
__global__ __launch_bounds__(256) void k_agg(
    const float* __restrict__ v, const float2* __restrict__ coefCW,
    float2* __restrict__ aggN)
{
    const int lane  = threadIdx.x & 63;
    const int C     = blockIdx.x * 4 + (threadIdx.x >> 6);
    const int vbase = C * (VC * DIM);
    const int cbase = __builtin_amdgcn_readfirstlane(C * VC);

    float nx = 0.f, ny = 0.f;
    for (int t0 = 0; t0 < VC; t0 += 8) {
        float2 cw[8], vv[8];
        #pragma unroll
        for (int u = 0; u < 8; ++u) cw[u] = coefCW[cbase + t0 + u];
        #pragma unroll
        for (int u = 0; u < 8; ++u)
            vv[u] = *((const float2*)(v + vbase + (t0 + u) * DIM) + lane);
        #pragma unroll
        for (int u = 0; u < 8; ++u) {
            nx = cw[u].x * nx + cw[u].y * vv[u].x;
            ny = cw[u].x * ny + cw[u].y * vv[u].y;
        }
    }
    aggN[C * (DIM / 2) + lane] = make_float2(nx, ny);
}

// ---------------------------------------------------------------------------
// k_pref: per row, exclusive prefix scan of aggN over 64 chunks (in place),
// combine factor f1 = exp(pM[2C] - pM[2C+2]). Prefetch 8 ahead.
// ---------------------------------------------------------------------------
__global__ __launch_bounds__(128) void k_pref(
    float* __restrict__ aggN, const float* __restrict__ pM)
{
    const int row = blockIdx.x;
    const int d   = threadIdx.x;
    float state = 0.f;
    for (int C0 = 0; C0 < VPR; C0 += 8) {
        float nb[8], f1[8];
        #pragma unroll
        for (int u = 0; u < 8; ++u) {
            const int C = C0 + u;
            nb[u] = aggN[(row * VPR + C) * DIM + d];
            const int Cg = row * VPR + C;
            const float mp  = pM[2 * Cg];
            const bool last = (C == VPR - 1);
            const float mp2 = last ? 0.f : pM[2 * Cg + 2];
            f1[u] = last ? 0.f : __expf(mp - mp2);
        }
        #pragma unroll
        for (int u = 0; u < 8; ++u) {
            const float nc = nb[u];
            aggN[(row * VPR + C0 + u) * DIM + d] = state;
            state = state * f1[u] + nc;
        }
    }
}

// ---------------------------------------------------------------------------
// k_out: per vector chunk (one wave, lane owns 2 dims): replay the global
// recurrence seeded with the exclusive prefixes; y_t = n_t * rcp(d_t).
// ---------------------------------------------------------------------------
__global__ __launch_bounds__(256) void k_out(
    const float* __restrict__ v, const float2* __restrict__ coefCW,
    const float2* __restrict__ preN, const float* __restrict__ pD,
    float* __restrict__ y)
{
    const int lane  = threadIdx.x & 63;
    const int C     = blockIdx.x * 4 + (threadIdx.x >> 6);
    const int vbase = C * (VC * DIM);
    const int cbase = __builtin_amdgcn_readfirstlane(C * VC);

    float2 n  = preN[C * (DIM / 2) + lane];
    float dch = pD[2 * C];

    for (int t0 = 0; t0 < VC; t0 += 8) {
        float2 cw[8], vv[8];
        #pragma unroll
        for (int u = 0; u < 8; ++u) cw[u] = coefCW[cbase + t0 + u];
        #pragma unroll
        for (int u = 0; u < 8; ++u)
            vv[u] = *((const float2*)(v + vbase + (t0 + u) * DIM) + lane);
        #pragma unroll
        for (int u = 0; u < 8; ++u) {
            n.x = cw[u].x * n.x + cw[u].y * vv[u].x;
            n.y = cw[u].x * n.y + cw[u].y * vv[u].y;
            dch = cw[u].x * dch + cw[u].y;
            const float rd = __builtin_amdgcn_rcpf(dch);
            *((float2*)(y + vbase + (t0 + u) * DIM) + lane) =
                make_float2(n.x * rd, n.y * rd);
        }
    }
}

// ---------------------------------------------------------------------------
extern "C" void kernel_launch(void* const* d_in, const int* in_sizes, int n_in,
                              void* d_out, int out_size, void* d_ws, size_t ws_size,
                              hipStream_t stream) {
    const float* q = (const float*)d_in[0];
    const float* k = (const float*)d_in[1];
    const float* v = (const float*)d_in[2];
    float* y  = (float*)d_out;
    float* ws = (float*)d_ws;

    // ws layout (floats):
    //  coefCW : 524288   (float2[262144], global per-timestep (c,w))
    //  pM,pD  : 8192 each (exclusive scalar prefixes at sub-chunk grain)
    //  cM,cD  : 8192 each (sub-chunk local max / denom)
    //  U      : 524288   (alpha uses first 262144; aggN reuses all of it)
    float*  coefCWf = ws;
    float*  pM      = coefCWf + 2 * ROWS * NSEQ;       // 524288
    float*  pD      = pM + NSC;
    float*  cM      = pD + NSC;
    float*  cD      = cM + NSC;
    float*  U       = cD + NSC;                        // union region
    float*  alphaA  = U;                               // 262144 floats
    float*  aggNf   = U;                               // 524288 floats (after k_scan)
    float2* coefCW  = (float2*)coefCWf;
    float2* aggN2   = (float2*)aggNf;
    // total: 1,081,344 floats = 4.33 MB

    k_alpha<<<(ROWS * NSEQ / 64) / 4, 256, 0, stream>>>(q, k, alphaA, cM, cD);
    k_scan<<<ROWS, 256, 0, stream>>>(alphaA, cM, cD, pM, pD, coefCW);
    k_agg<<<NVC / 4, 256, 0, stream>>>(v, coefCW, aggN2);
    k_pref<<<ROWS, DIM, 0, stream>>>(aggNf, pM);
    k_out<<<NVC / 4, 256, 0, stream>>>(v, coefCW, aggN2, pD, y);
}

// Round 5
// 159.630 us; speedup vs baseline: 1.1983x; 1.1983x over previous
//
#include <hip/hip_runtime.h>
#include <math.h>
#include <stdint.h>

// B=4, H=16, N=4096, D=128 -> 64 independent scan rows of length 4096.
static constexpr int ROWS = 64;
static constexpr int NSEQ = 4096;
static constexpr int DIM  = 128;
static constexpr int SC   = 16;              // scalar sub-chunk length (= 1 wave)
static constexpr int SPR  = NSEQ / SC;       // 256 sub-chunks per row
static constexpr int NSC  = ROWS * SPR;      // 16384 sub-chunks
static constexpr int VC   = 64;              // vector chunk length
static constexpr int VPR  = NSEQ / VC;       // 64 chunks per row
static constexpr int NVC  = ROWS * VPR;      // 4096 vector chunks
static constexpr int SPC  = VC / SC;         // sub-chunks per vector chunk = 4

typedef __attribute__((address_space(3))) uint32_t  lds_u32;
typedef const __attribute__((address_space(1))) uint32_t g_u32;

// ---------------------------------------------------------------------------
// k_alpha v3: async-staged. Block=128 thr, tile=32 timesteps.
// Stage q-tile (16KB) + k-tile (16KB) into LDS with global_load_lds dwordx4
// (zero VGPR cost, 16-deep queue per wave). LDS is linear-dest with
// INVERSE-SWIZZLED global source; reads XOR-swizzle (byte ^= (t&7)<<4) so the
// 512B-row column read is bank-conflict-free (rule #21 / G4).
// Compute: 4 lanes per timestep, 32 floats each, dot in-lane, 2 shfl combine.
// Per-wave (=16-timestep sub-chunk) stats via 4-level butterfly.
// ---------------------------------------------------------------------------
__global__ __launch_bounds__(128) void k_alpha(
    const float* __restrict__ q, const float* __restrict__ k,
    float* __restrict__ alpha, float* __restrict__ cM, float* __restrict__ cD)
{
    __shared__ float lds[8192];              // q: [0,4096) floats, k: [4096,8192)
    const int l    = threadIdx.x & 63;
    const int w    = threadIdx.x >> 6;       // wave 0/1
    const int tile = blockIdx.x;             // 32-timestep tile
    const int b4   = tile * (32 * DIM);      // global float base of tile

    // ---- stage: each wave covers 8KB of q and 8KB of k (8+8 instructions)
    #pragma unroll
    for (int i = 0; i < 8; ++i) {
        const int p  = w * 8192 + i * 1024 + l * 16;         // linear LDS byte
        const int ps = p ^ (((p >> 9) & 7) << 4);            // involution swz
        __builtin_amdgcn_global_load_lds((g_u32*)(q + b4 + (ps >> 2)),
                                         (lds_u32*)&lds[(w * 8192 + i * 1024) >> 2],
                                         16, 0, 0);
    }
    #pragma unroll
    for (int i = 0; i < 8; ++i) {
        const int p  = w * 8192 + i * 1024 + l * 16;
        const int ps = p ^ (((p >> 9) & 7) << 4);
        __builtin_amdgcn_global_load_lds((g_u32*)(k + b4 + (ps >> 2)),
                                         (lds_u32*)&lds[4096 + ((w * 8192 + i * 1024) >> 2)],
                                         16, 0, 0);
    }
    asm volatile("s_waitcnt vmcnt(0)" ::: "memory");
    __syncthreads();

    // ---- compute: t = w*16 + (l>>2), chunk c = l&3 (32 floats per lane)
    const int tl = w * 16 + (l >> 2);
    const int c  = l & 3;
    const int sw = (tl & 7) << 4;
    float acc = 0.f;
    #pragma unroll
    for (int j = 0; j < 8; ++j) {
        const int off = tl * 512 + ((c * 128 + j * 16) ^ sw);   // swizzled read
        const float4 qv = *(const float4*)((const char*)lds + off);
        const float4 kv = *(const float4*)((const char*)lds + 16384 + off);
        acc += qv.x * kv.x + qv.y * kv.y + qv.z * kv.z + qv.w * kv.w;
    }
    acc += __shfl_xor(acc, 1);
    acc += __shfl_xor(acc, 2);               // all 4 lanes of t-group hold alpha_t

    // per-wave stats over its 16 timesteps (sub-chunk = tile*2 + w)
    float M = acc;
    #pragma unroll
    for (int m = 4; m <= 32; m <<= 1) M = fmaxf(M, __shfl_xor(M, m));
    float e = (c == 0) ? __expf(acc - M) : 0.f;
    #pragma unroll
    for (int m = 4; m <= 32; m <<= 1) e += __shfl_xor(e, m);

    if (c == 0) alpha[tile * 32 + tl] = acc;
    if (l == 0) { cM[tile * 2 + w] = M; cD[tile * 2 + w] = e; }
}

// ---------------------------------------------------------------------------
// k_scan: per row (64 blocks):
//  1) thread-0 serial exclusive scan over 256 sub-chunks -> pM,pD (+LDS copy)
//  2) 16-lane-group prefix-max scan per sub-chunk -> coefCW[t] = (c_t, w_t)
// ---------------------------------------------------------------------------
__global__ __launch_bounds__(256) void k_scan(
    const float* __restrict__ alpha, const float* __restrict__ cM,
    const float* __restrict__ cD,
    float* __restrict__ pM, float* __restrict__ pD, float2* __restrict__ coefCW)
{
    __shared__ float lM[SPR], lD[SPR], lpM[SPR];
    const int row = blockIdx.x;
    const int tid = threadIdx.x;

    lM[tid] = cM[row * SPR + tid];
    lD[tid] = cD[row * SPR + tid];
    __syncthreads();

    if (tid == 0) {
        float m = -INFINITY, d = 0.f;
        for (int sl = 0; sl < SPR; ++sl) {
            lpM[sl] = m;
            pM[row * SPR + sl] = m; pD[row * SPR + sl] = d;
            const float M = lM[sl], D = lD[sl];
            const float mn = fmaxf(m, M);
            d = d * __expf(m - mn) + D * __expf(M - mn);
            m = mn;
        }
    }
    __syncthreads();

    const int li = tid & 15, grp = tid >> 4;          // 16 groups of 16 lanes
    for (int sl = grp; sl < SPR; sl += 16) {
        const int s = row * SPR + sl;
        const float a = alpha[s * SC + li];
        // inclusive prefix max over the 16 lanes
        float m = a;
        #pragma unroll
        for (int d = 1; d < 16; d <<= 1) {
            const float o = __shfl_up(m, d, 16);
            if (li >= d) m = fmaxf(m, o);
        }
        const float carry = lpM[sl];
        const float mf = fmaxf(m, carry);             // running max incl. carry
        float mp = __shfl_up(mf, 1, 16);
        if (li == 0) mp = carry;                      // m_{t-1}
        const float cc = __expf(mp - mf);             // exp(-inf)=0 at very start
        const float wt = __expf(a - mf);
        coefCW[s * SC + li] = make_float2(cc, wt);
    }
}

// ---------------------------------------------------------------------------
// k_agg: per vector chunk (one wave, lane owns 2 dims): n'_C via the global
// coefficient recurrence seeded 0 (result normalized at chunk-end global max).
// ---------------------------------------------------------------------------
__global__ __launch_bounds__(256) void k_agg(
    const float* __restrict__ v, const float2* __restrict__ coefCW,
    float2* __restrict__ aggN)
{
    const int lane  = threadIdx.x & 63;
    const int C     = blockIdx.x * 4 + (threadIdx.x >> 6);
    const int vbase = C * (VC * DIM);
    const int cbase = __builtin_amdgcn_readfirstlane(C * VC);

    float nx = 0.f, ny = 0.f;
    for (int t0 = 0; t0 < VC; t0 += 8) {
        float2 cw[8], vv[8];
        #pragma unroll
        for (int u = 0; u < 8; ++u) cw[u] = coefCW[cbase + t0 + u];
        #pragma unroll
        for (int u = 0; u < 8; ++u)
            vv[u] = *((const float2*)(v + vbase + (t0 + u) * DIM) + lane);
        #pragma unroll
        for (int u = 0; u < 8; ++u) {
            nx = cw[u].x * nx + cw[u].y * vv[u].x;
            ny = cw[u].x * ny + cw[u].y * vv[u].y;
        }
    }
    aggN[C * (DIM / 2) + lane] = make_float2(nx, ny);
}

// ---------------------------------------------------------------------------
// k_pref: per row, exclusive prefix scan of aggN over 64 chunks (in place),
// combine factor f1 = exp(pM[4C] - pM[4C+4]) (sub-chunk stride = 4 now).
// ---------------------------------------------------------------------------
__global__ __launch_bounds__(128) void k_pref(
    float* __restrict__ aggN, const float* __restrict__ pM)
{
    const int row = blockIdx.x;
    const int d   = threadIdx.x;
    float state = 0.f;
    for (int C0 = 0; C0 < VPR; C0 += 8) {
        float nb[8], f1[8];
        #pragma unroll
        for (int u = 0; u < 8; ++u) {
            const int C  = C0 + u;
            const int Cg = row * VPR + C;
            nb[u] = aggN[Cg * DIM + d];
            const bool last = (C == VPR - 1);
            const float mp  = pM[SPC * Cg];
            const float mp2 = last ? 0.f : pM[SPC * Cg + SPC];
            f1[u] = last ? 0.f : __expf(mp - mp2);
        }
        #pragma unroll
        for (int u = 0; u < 8; ++u) {
            const float nc = nb[u];
            aggN[(row * VPR + C0 + u) * DIM + d] = state;
            state = state * f1[u] + nc;
        }
    }
}

// ---------------------------------------------------------------------------
// k_out: per vector chunk (one wave, lane owns 2 dims): replay the global
// recurrence seeded with the exclusive prefixes; y_t = n_t * rcp(d_t).
// ---------------------------------------------------------------------------
__global__ __launch_bounds__(256) void k_out(
    const float* __restrict__ v, const float2* __restrict__ coefCW,
    const float2* __restrict__ preN, const float* __restrict__ pD,
    float* __restrict__ y)
{
    const int lane  = threadIdx.x & 63;
    const int C     = blockIdx.x * 4 + (threadIdx.x >> 6);
    const int vbase = C * (VC * DIM);
    const int cbase = __builtin_amdgcn_readfirstlane(C * VC);

    float2 n  = preN[C * (DIM / 2) + lane];
    float dch = pD[SPC * C];

    for (int t0 = 0; t0 < VC; t0 += 8) {
        float2 cw[8], vv[8];
        #pragma unroll
        for (int u = 0; u < 8; ++u) cw[u] = coefCW[cbase + t0 + u];
        #pragma unroll
        for (int u = 0; u < 8; ++u)
            vv[u] = *((const float2*)(v + vbase + (t0 + u) * DIM) + lane);
        #pragma unroll
        for (int u = 0; u < 8; ++u) {
            n.x = cw[u].x * n.x + cw[u].y * vv[u].x;
            n.y = cw[u].x * n.y + cw[u].y * vv[u].y;
            dch = cw[u].x * dch + cw[u].y;
            const float rd = __builtin_amdgcn_rcpf(dch);
            *((float2*)(y + vbase + (t0 + u) * DIM) + lane) =
                make_float2(n.x * rd, n.y * rd);
        }
    }
}

// ---------------------------------------------------------------------------
extern "C" void kernel_launch(void* const* d_in, const int* in_sizes, int n_in,
                              void* d_out, int out_size, void* d_ws, size_t ws_size,
                              hipStream_t stream) {
    const float* q = (const float*)d_in[0];
    const float* k = (const float*)d_in[1];
    const float* v = (const float*)d_in[2];
    float* y  = (float*)d_out;
    float* ws = (float*)d_ws;

    // ws layout (floats):
    //  coefCW : 524288    (float2[262144], global per-timestep (c,w))
    //  pM,pD  : 16384 each (exclusive scalar prefixes, SC=16 grain)
    //  cM,cD  : 16384 each (sub-chunk local max / denom)
    //  U      : 524288    (alpha uses first 262144; aggN reuses all of it)
    float*  coefCWf = ws;
    float*  pM      = coefCWf + 2 * ROWS * NSEQ;       // +524288
    float*  pD      = pM + NSC;
    float*  cM      = pD + NSC;
    float*  cD      = cM + NSC;
    float*  U       = cD + NSC;
    float*  alphaA  = U;                               // 262144 floats
    float*  aggNf   = U;                               // 524288 floats (after k_scan)
    float2* coefCW  = (float2*)coefCWf;
    float2* aggN2   = (float2*)aggNf;
    // total: 1,114,112 floats = 4.46 MB

    k_alpha<<<ROWS * NSEQ / 32, 128, 0, stream>>>(q, k, alphaA, cM, cD);
    k_scan<<<ROWS, 256, 0, stream>>>(alphaA, cM, cD, pM, pD, coefCW);
    k_agg<<<NVC / 4, 256, 0, stream>>>(v, coefCW, aggN2);
    k_pref<<<ROWS, DIM, 0, stream>>>(aggNf, pM);
    k_out<<<NVC / 4, 256, 0, stream>>>(v, coefCW, aggN2, pD, y);
}